// Round 1
// baseline (881.641 us; speedup 1.0000x reference)
//
#include <hip/hip_runtime.h>
#include <math.h>

#define BATCH 32
#define SEQ   2048
#define DH    128
#define QT    64        // q rows per block (16 per wave)
#define KT    64        // k cols per iteration
#define KSTR  136       // K/Q LDS row stride in halves (128+8): b128 reads 2-way (free)
#define VSTR  72        // Vt LDS row stride in halves (64+8)
#define PSTR  72        // P LDS row stride in halves
#define SCALE 0.08838834764831845f   // 1/sqrt(128)

typedef _Float16 f16;
typedef _Float16 f16x4 __attribute__((ext_vector_type(4)));
typedef _Float16 f16x8 __attribute__((ext_vector_type(8)));
typedef float    f32x4 __attribute__((ext_vector_type(4)));

__global__ __launch_bounds__(256, 3)
void ScaledDotProductAttention_46720654246409_kernel(
    const float* __restrict__ q, const float* __restrict__ k,
    const float* __restrict__ v, const float* __restrict__ mask,
    float* __restrict__ out)
{
    __shared__ f16 ks[KT * KSTR];        // K tile (also Q staging before loop): 17408 B
    __shared__ f16 vs[DH * VSTR];        // V tile transposed Vt[d][j]:          18432 B
    __shared__ f16 ps[4 * 16 * PSTR];    // per-wave P tiles:                     9216 B

    const int tid  = threadIdx.x;
    const int wv   = tid >> 6;
    const int lane = tid & 63;
    const int quad = lane >> 4;
    const int l16  = lane & 15;
    const int srow = tid >> 5;   // 0..7 staging row
    const int scol = tid & 31;   // 0..31 staging col group

    const int bidx = blockIdx.x;
    const int b    = bidx >> 5;            // 32 q-blocks per batch
    const int q0   = (bidx & 31) * QT;

    const size_t qkvBase = (size_t)b * SEQ * DH;
    const size_t mBase   = (size_t)b * SEQ * SEQ;

    // ---- stage Q (fp32 -> fp16) through ks, pull A-frags to registers ----
    #pragma unroll
    for (int p = 0; p < 8; ++p) {
        int r = p * 8 + srow;
        f32x4 x = *(const f32x4*)&q[qkvBase + (size_t)(q0 + r) * DH + scol * 4];
        f16x4 h = { (f16)x.x, (f16)x.y, (f16)x.z, (f16)x.w };
        *(f16x4*)&ks[r * KSTR + scol * 4] = h;
    }
    __syncthreads();

    f16x8 aq[4];   // A[m=l16][d = dc*32 + quad*8 + j]
    #pragma unroll
    for (int dc = 0; dc < 4; ++dc)
        aq[dc] = *(const f16x8*)&ks[(wv * 16 + l16) * KSTR + dc * 32 + quad * 8];
    __syncthreads();

    float m_run[4] = { -INFINITY, -INFINITY, -INFINITY, -INFINITY };
    float l_run[4] = { 0.f, 0.f, 0.f, 0.f };
    f32x4 o[8];
    #pragma unroll
    for (int f = 0; f < 8; ++f) o[f] = (f32x4){0.f, 0.f, 0.f, 0.f};

    for (int kt = 0; kt < SEQ / KT; ++kt) {
        const int k0 = kt * KT;

        // mask prefetch into registers (overlaps with staging below)
        float mk[4][4];
        #pragma unroll
        for (int f = 0; f < 4; ++f)
            #pragma unroll
            for (int r = 0; r < 4; ++r)
                mk[f][r] = mask[mBase + (size_t)(q0 + wv*16 + quad*4 + r) * SEQ
                                + k0 + f*16 + l16];

        // stage K tile (row-major, padded)
        #pragma unroll
        for (int p = 0; p < 8; ++p) {
            int r = p * 8 + srow;
            f32x4 x = *(const f32x4*)&k[qkvBase + (size_t)(k0 + r) * DH + scol * 4];
            f16x4 h = { (f16)x.x, (f16)x.y, (f16)x.z, (f16)x.w };
            *(f16x4*)&ks[r * KSTR + scol * 4] = h;
        }
        // stage V tile transposed: Vt[d][j]; stride-32 d per lane keeps banks clean
        #pragma unroll
        for (int p = 0; p < 8; ++p) {
            int j = p * 8 + srow;
            const float* vr = &v[qkvBase + (size_t)(k0 + j) * DH];
            #pragma unroll
            for (int i = 0; i < 4; ++i)
                vs[(scol + 32*i) * VSTR + j] = (f16)vr[scol + 32*i];
        }
        __syncthreads();

        // ---- S = Q K^T : 4 n-tiles x 4 d-chunks ----
        f32x4 sc[4];
        #pragma unroll
        for (int f = 0; f < 4; ++f) {
            sc[f] = (f32x4){0.f, 0.f, 0.f, 0.f};
            #pragma unroll
            for (int dc = 0; dc < 4; ++dc) {
                f16x8 bk = *(const f16x8*)&ks[(f*16 + l16) * KSTR + dc*32 + quad*8];
                sc[f] = __builtin_amdgcn_mfma_f32_16x16x32_f16(aq[dc], bk, sc[f], 0, 0, 0);
            }
        }

        // ---- online softmax (row = quad*4 + r, spans 16 lanes) ----
        float pj[4][4];
        float alpha[4];
        #pragma unroll
        for (int r = 0; r < 4; ++r) {
            float sf[4];
            #pragma unroll
            for (int f = 0; f < 4; ++f) sf[f] = sc[f][r] * SCALE * mk[f][r];
            float mx = fmaxf(fmaxf(sf[0], sf[1]), fmaxf(sf[2], sf[3]));
            #pragma unroll
            for (int off = 1; off < 16; off <<= 1)
                mx = fmaxf(mx, __shfl_xor(mx, off, 16));
            float mn = fmaxf(m_run[r], mx);
            float al = __expf(m_run[r] - mn);     // first iter: exp(-inf) = 0
            float sum = 0.f;
            #pragma unroll
            for (int f = 0; f < 4; ++f) { pj[f][r] = __expf(sf[f] - mn); sum += pj[f][r]; }
            #pragma unroll
            for (int off = 1; off < 16; off <<= 1)
                sum += __shfl_xor(sum, off, 16);
            m_run[r] = mn;
            l_run[r] = l_run[r] * al + sum;
            alpha[r] = al;
        }

        // ---- P: C-layout -> LDS -> A-layout (per-wave region, in-wave DS order) ----
        #pragma unroll
        for (int f = 0; f < 4; ++f)
            #pragma unroll
            for (int r = 0; r < 4; ++r)
                ps[(wv*16 + quad*4 + r) * PSTR + f*16 + l16] = (f16)pj[f][r];
        asm volatile("s_waitcnt lgkmcnt(0)" ::: "memory");

        f16x8 ap0 = *(const f16x8*)&ps[(wv*16 + l16) * PSTR + quad*8];
        f16x8 ap1 = *(const f16x8*)&ps[(wv*16 + l16) * PSTR + 32 + quad*8];

        // ---- O = O*alpha + P V : 8 c-tiles x 2 k-chunks ----
        #pragma unroll
        for (int f = 0; f < 8; ++f) {
            #pragma unroll
            for (int r = 0; r < 4; ++r) o[f][r] *= alpha[r];
            f16x8 bv0 = *(const f16x8*)&vs[(f*16 + l16) * VSTR + quad*8];
            f16x8 bv1 = *(const f16x8*)&vs[(f*16 + l16) * VSTR + 32 + quad*8];
            o[f] = __builtin_amdgcn_mfma_f32_16x16x32_f16(ap0, bv0, o[f], 0, 0, 0);
            o[f] = __builtin_amdgcn_mfma_f32_16x16x32_f16(ap1, bv1, o[f], 0, 0, 0);
        }
        __syncthreads();
    }

    // ---- epilogue: normalize and store ----
    #pragma unroll
    for (int r = 0; r < 4; ++r) {
        float inv = 1.0f / l_run[r];
        #pragma unroll
        for (int f = 0; f < 8; ++f)
            out[qkvBase + (size_t)(q0 + wv*16 + quad*4 + r) * DH + f*16 + l16]
                = o[f][r] * inv;
    }
}

extern "C" void kernel_launch(void* const* d_in, const int* in_sizes, int n_in,
                              void* d_out, int out_size, void* d_ws, size_t ws_size,
                              hipStream_t stream) {
    const float* q    = (const float*)d_in[0];
    const float* k    = (const float*)d_in[1];
    const float* v    = (const float*)d_in[2];
    const float* mask = (const float*)d_in[3];
    float* out = (float*)d_out;

    dim3 grid(BATCH * (SEQ / QT));   // 32 * 32 = 1024 blocks
    dim3 block(256);
    hipLaunchKernelGGL(ScaledDotProductAttention_46720654246409_kernel,
                       grid, block, 0, stream, q, k, v, mask, out);
}